// Round 6
// baseline (302.324 us; speedup 1.0000x reference)
//
#include <hip/hip_runtime.h>

// ---------------------------------------------------------------------------
// Fused NeRF MLP forward: 262144 rows, 63-in, 8x256 hidden + skip at L4->L5,
// 4-dim output. fp16 MFMA (16x16x32) with fp32 accumulation.
//
// R6 = R5 (512 thr, 8 waves, 2 blocks/CU) with the wave tile rotated to
// 32 rows x 64 cols: acc[2][4] (same 32 accum regs) but A-fragment LDS reads
// per wave halve (2 mf instead of 4). R5 counters showed the LDS pipe
// (A-reads 29% + conflicts 19% of CU cycles) co-saturated with MFMA (48%).
// Cost: each B-fragment now loaded by 2 waves (L2-cached, pipeline-hidden).
// ---------------------------------------------------------------------------

typedef _Float16 h8 __attribute__((ext_vector_type(8)));
typedef float f4 __attribute__((ext_vector_type(4)));

// fragment-linear weight offsets, in halves:
// L0 K=64, L1..L4 K=256, L5 K=320, L6,L7 K=256, OUT K=256 (NF=1, n padded to 16)
#define OFF_L0   0
#define OFF_L1   16384
#define OFF_L2   81920
#define OFF_L3   147456
#define OFF_L4   212992
#define OFF_L5   278528
#define OFF_L6   360448
#define OFF_L7   425984
#define OFF_OUT  491520
#define TOT_HALVES 495616
#define TOT_GROUPS (TOT_HALVES / 8)   // 61952

__global__ void nerf_prep(const float* __restrict__ W0, const float* __restrict__ W1,
                          const float* __restrict__ W2, const float* __restrict__ W3,
                          const float* __restrict__ W4, const float* __restrict__ W5,
                          const float* __restrict__ W6, const float* __restrict__ W7,
                          const float* __restrict__ Wout, _Float16* __restrict__ wf)
{
    int g = blockIdx.x * 256 + threadIdx.x;     // one 8-half fragment group
    if (g >= TOT_GROUPS) return;

    const int bounds[10] = {0, 2048, 10240, 18432, 26624, 34816, 45056, 53248, 61440, 61952};
    const float* Ws[9] = {W0, W1, W2, W3, W4, W5, W6, W7, Wout};

    int L = 0;
    while (L < 8 && g >= bounds[L + 1]) ++L;

    int t    = g - bounds[L];
    int lane = t & 63;
    int q    = t >> 6;
    int NF   = (L == 8) ? 1 : 16;
    int nf   = q % NF;
    int ks   = q / NF;
    int n    = nf * 16 + (lane & 15);
    int k0   = ks * 32 + (lane >> 4) * 8;

    const float* W = Ws[L];
    h8 v;
#pragma unroll
    for (int i = 0; i < 8; ++i) {
        int k = k0 + i;
        float val = 0.f;
        if (L == 0) {
            if (k < 63) val = W[k * 256 + n];                 // 63x256, pad k=63
        } else if (L == 5) {
            // k' < 256 -> h part (orig row 63+k'); k' >= 256 -> x part (orig row k'-256)
            if (k < 256)            val = W[(63 + k) * 256 + n];
            else if ((k - 256) < 63) val = W[(k - 256) * 256 + n];
        } else if (L == 8) {
            if (n < 4) val = W[k * 4 + n];                    // 256x4, pad n to 16
        } else {
            val = W[k * 256 + n];                             // 256x256
        }
        v[i] = (_Float16)val;
    }
    *(h8*)(wf + (size_t)g * 8) = v;
}

// slot in [0,16): which 16-col fragment of the 256-col layer output
__device__ __forceinline__ const h8* bfrag_ptr(const _Float16* __restrict__ w,
                                               int ks, int slot, int lane)
{
    return (const h8*)(w + (size_t)((ks * 16 + slot) * 64 + lane) * 8);
}

// MODE: 0 = A from hbuf, 1 = A from xbuf (layer 0), 2 = hbuf then xbuf (layer 5)
// Wave tile: rows (wid&1)*32 + [0,32), cols (wid>>1)*64 + [0,64).
// pf: depth-2 prefetch buffers (this wave's 4 col-slots).
template <int KSTEPS, int MODE, bool LAST>
__device__ __forceinline__ void mlp_layer(_Float16 (&hbuf)[64][264], _Float16 (&xbuf)[64][72],
                                          const _Float16* __restrict__ wfrag,
                                          const _Float16* __restrict__ wnext,
                                          const float* __restrict__ bias,
                                          int wid, int lane, h8 (&pf)[2][4])
{
    const int lg = lane >> 4, ln = lane & 15;
    const int rbase = (wid & 1) * 32;        // wave's 32-row half
    const int cbase = (wid >> 1) * 64;       // wave's 64-col slice (slots cslot..cslot+3)
    const int cslot = (wid >> 1) * 4;

    // bias early (no fresh global load in the epilogue)
    float bv[4];
#pragma unroll
    for (int nf = 0; nf < 4; ++nf) bv[nf] = bias[cbase + nf * 16 + ln];

    f4 acc[2][4];
#pragma unroll
    for (int mf = 0; mf < 2; ++mf)
#pragma unroll
        for (int nf = 0; nf < 4; ++nf)
#pragma unroll
            for (int i = 0; i < 4; ++i) acc[mf][nf][i] = 0.f;

#pragma unroll
    for (int ks = 0; ks < KSTEPS; ++ks) {
#pragma unroll
        for (int mf = 0; mf < 2; ++mf) {
            const int arow = rbase + mf * 16 + ln;
            const _Float16* ap;
            if constexpr (MODE == 1) {
                ap = &xbuf[arow][ks * 32 + lg * 8];
            } else if constexpr (MODE == 2) {
                ap = (ks < 8) ? &hbuf[arow][ks * 32 + lg * 8]
                              : &xbuf[arow][(ks - 8) * 32 + lg * 8];
            } else {
                ap = &hbuf[arow][ks * 32 + lg * 8];
            }
            h8 afr = *(const h8*)ap;
#pragma unroll
            for (int nf = 0; nf < 4; ++nf)
                acc[mf][nf] = __builtin_amdgcn_mfma_f32_16x16x32_f16(afr, pf[ks & 1][nf], acc[mf][nf], 0, 0, 0);
        }
        // refill the buffer just consumed: ks+2 of this layer, or ks=0/1 of next
        if (ks + 2 < KSTEPS) {
#pragma unroll
            for (int nf = 0; nf < 4; ++nf)
                pf[ks & 1][nf] = *bfrag_ptr(wfrag, ks + 2, cslot + nf, lane);
        } else if constexpr (!LAST) {
#pragma unroll
            for (int nf = 0; nf < 4; ++nf)
                pf[ks & 1][nf] = *bfrag_ptr(wnext, ks + 2 - KSTEPS, cslot + nf, lane);
        }
    }

    __syncthreads();   // everyone done reading hbuf -> safe to overwrite in place

#pragma unroll
    for (int nf = 0; nf < 4; ++nf) {
#pragma unroll
        for (int mf = 0; mf < 2; ++mf) {
#pragma unroll
            for (int i = 0; i < 4; ++i) {
                float v = acc[mf][nf][i] + bv[nf];  // bias in fp32
                v = fmaxf(v, 0.f);                  // relu in fp32
                // C layout (m89-verified): row = (lane>>4)*4 + reg, col = lane&15
                hbuf[rbase + mf * 16 + lg * 4 + i][cbase + nf * 16 + ln] = (_Float16)v;
            }
        }
    }
    __syncthreads();
}

__global__ __launch_bounds__(512, 4) void nerf_fused(
    const float* __restrict__ x,
    const float* __restrict__ b0, const float* __restrict__ b1, const float* __restrict__ b2,
    const float* __restrict__ b3, const float* __restrict__ b4, const float* __restrict__ b5,
    const float* __restrict__ b6, const float* __restrict__ b7, const float* __restrict__ bout,
    const _Float16* __restrict__ wf,
    float* __restrict__ out)
{
    __shared__ _Float16 hbuf[64][264];   // 256 + 8 pad halves per row (proven layout)
    __shared__ _Float16 xbuf[64][72];    // 64 (63 real + 1 zero) + pad

    const int tid  = threadIdx.x;
    const int wid  = tid >> 6;           // 0..7
    const int lane = tid & 63;
    const int lg   = lane >> 4, ln = lane & 15;
    const int row0 = blockIdx.x * 64;
    const int cslot = (wid >> 1) * 4;

    // prologue: issue L0's ks=0,1 B-frag loads first (in flight during x-staging)
    h8 pf[2][4];
#pragma unroll
    for (int s = 0; s < 2; ++s)
#pragma unroll
        for (int nf = 0; nf < 4; ++nf)
            pf[s][nf] = *bfrag_ptr(wf + OFF_L0, s, cslot + nf, lane);

    // stage x[:, 0:63] -> fp16, zero-pad col 63
    for (int idx = tid; idx < 64 * 64; idx += 512) {
        int r = idx >> 6, c = idx & 63;
        float v = (c < 63) ? x[(size_t)(row0 + r) * 90 + c] : 0.f;
        xbuf[r][c] = (_Float16)v;
    }
    __syncthreads();

    mlp_layer<2, 1, false>(hbuf, xbuf, wf + OFF_L0, wf + OFF_L1, b0, wid, lane, pf);
    mlp_layer<8, 0, false>(hbuf, xbuf, wf + OFF_L1, wf + OFF_L2, b1, wid, lane, pf);
    mlp_layer<8, 0, false>(hbuf, xbuf, wf + OFF_L2, wf + OFF_L3, b2, wid, lane, pf);
    mlp_layer<8, 0, false>(hbuf, xbuf, wf + OFF_L3, wf + OFF_L4, b3, wid, lane, pf);
    mlp_layer<8, 0, false>(hbuf, xbuf, wf + OFF_L4, wf + OFF_L5, b4, wid, lane, pf);
    mlp_layer<10, 2, false>(hbuf, xbuf, wf + OFF_L5, wf + OFF_L6, b5, wid, lane, pf);
    mlp_layer<8, 0, false>(hbuf, xbuf, wf + OFF_L6, wf + OFF_L7, b6, wid, lane, pf);
    mlp_layer<8, 0, true>(hbuf, xbuf, wf + OFF_L7, wf + OFF_L7, b7, wid, lane, pf);

    // output layer 256 -> 4 (padded to 16 cols): waves 0..3 each do 16 rows
    if (wid < 4) {
        f4 oacc;
#pragma unroll
        for (int i = 0; i < 4; ++i) oacc[i] = 0.f;
#pragma unroll
        for (int ks = 0; ks < 8; ++ks) {
            h8 bfr = *(const h8*)(wf + OFF_OUT + (size_t)(ks * 64 + lane) * 8);
            h8 afr = *(const h8*)&hbuf[wid * 16 + ln][ks * 32 + lg * 8];
            oacc = __builtin_amdgcn_mfma_f32_16x16x32_f16(afr, bfr, oacc, 0, 0, 0);
        }
        if (ln < 4) {
            float bo = bout[ln];
#pragma unroll
            for (int i = 0; i < 4; ++i) {
                int r = row0 + wid * 16 + lg * 4 + i;
                out[(size_t)r * 4 + ln] = oacc[i] + bo;
            }
        }
    }
}

extern "C" void kernel_launch(void* const* d_in, const int* in_sizes, int n_in,
                              void* d_out, int out_size, void* d_ws, size_t ws_size,
                              hipStream_t stream)
{
    const float* x = (const float*)d_in[0];
    const float* W[9];
    const float* b[9];
    for (int i = 0; i < 8; ++i) {
        W[i] = (const float*)d_in[1 + 2 * i];
        b[i] = (const float*)d_in[2 + 2 * i];
    }
    W[8] = (const float*)d_in[17];   // Wout
    b[8] = (const float*)d_in[18];   // bout

    _Float16* wf = (_Float16*)d_ws;

    nerf_prep<<<(TOT_GROUPS + 255) / 256, 256, 0, stream>>>(
        W[0], W[1], W[2], W[3], W[4], W[5], W[6], W[7], W[8], wf);

    nerf_fused<<<262144 / 64, 512, 0, stream>>>(
        x, b[0], b[1], b[2], b[3], b[4], b[5], b[6], b[7], b[8], wf,
        (float*)d_out);
}

// Round 7
// 237.463 us; speedup vs baseline: 1.2731x; 1.2731x over previous
//
#include <hip/hip_runtime.h>

// ---------------------------------------------------------------------------
// Fused NeRF MLP forward: 262144 rows, 63-in, 8x256 hidden + skip at L4->L5,
// 4-dim output. fp16 MFMA (16x16x32) with fp32 accumulation.
//
// R7 = R2 base (256 thr, 4 waves, wave = 64 rows x 64 cols, 3 blocks/CU)
// with three scheduling fixes:
//  1. barrier_nodrain(): lgkmcnt(0)-only barrier (no vmcnt drain) so the
//     cross-layer B-prefetch stays in flight across the 17 block barriers.
//  2. Depth-3 B-fragment pipeline pf[3][4] (rolling slot = global kstep % 3,
//     all indices compile-time) -> 2 full ks of MFMA lead over L2 latency.
//  3. s_setprio(1) around each ks's 16-MFMA burst (3 independent blocks/CU
//     give the scheduler role diversity - T5 applicability condition).
// R6 lesson: gm=2 doubles the B-stream into L2 saturation; R5 lesson: gn=8
// saturates the LDS pipe. R2's gn=4/gm=1 with all pipes ~43% is the base.
// ---------------------------------------------------------------------------

typedef _Float16 h8 __attribute__((ext_vector_type(8)));
typedef float f4 __attribute__((ext_vector_type(4)));

// fragment-linear weight offsets, in halves:
// L0 K=64, L1..L4 K=256, L5 K=320, L6,L7 K=256, OUT K=256 (NF=1, n padded to 16)
#define OFF_L0   0
#define OFF_L1   16384
#define OFF_L2   81920
#define OFF_L3   147456
#define OFF_L4   212992
#define OFF_L5   278528
#define OFF_L6   360448
#define OFF_L7   425984
#define OFF_OUT  491520
#define TOT_HALVES 495616
#define TOT_GROUPS (TOT_HALVES / 8)   // 61952

__global__ void nerf_prep(const float* __restrict__ W0, const float* __restrict__ W1,
                          const float* __restrict__ W2, const float* __restrict__ W3,
                          const float* __restrict__ W4, const float* __restrict__ W5,
                          const float* __restrict__ W6, const float* __restrict__ W7,
                          const float* __restrict__ Wout, _Float16* __restrict__ wf)
{
    int g = blockIdx.x * 256 + threadIdx.x;     // one 8-half fragment group
    if (g >= TOT_GROUPS) return;

    const int bounds[10] = {0, 2048, 10240, 18432, 26624, 34816, 45056, 53248, 61440, 61952};
    const float* Ws[9] = {W0, W1, W2, W3, W4, W5, W6, W7, Wout};

    int L = 0;
    while (L < 8 && g >= bounds[L + 1]) ++L;

    int t    = g - bounds[L];
    int lane = t & 63;
    int q    = t >> 6;
    int NF   = (L == 8) ? 1 : 16;
    int nf   = q % NF;
    int ks   = q / NF;
    int n    = nf * 16 + (lane & 15);
    int k0   = ks * 32 + (lane >> 4) * 8;

    const float* W = Ws[L];
    h8 v;
#pragma unroll
    for (int i = 0; i < 8; ++i) {
        int k = k0 + i;
        float val = 0.f;
        if (L == 0) {
            if (k < 63) val = W[k * 256 + n];                 // 63x256, pad k=63
        } else if (L == 5) {
            // k' < 256 -> h part (orig row 63+k'); k' >= 256 -> x part (orig row k'-256)
            if (k < 256)            val = W[(63 + k) * 256 + n];
            else if ((k - 256) < 63) val = W[(k - 256) * 256 + n];
        } else if (L == 8) {
            if (n < 4) val = W[k * 4 + n];                    // 256x4, pad n to 16
        } else {
            val = W[k * 256 + n];                             // 256x256
        }
        v[i] = (_Float16)val;
    }
    *(h8*)(wf + (size_t)g * 8) = v;
}

__device__ __forceinline__ const h8* bfrag_ptr(const _Float16* __restrict__ w,
                                               int ks, int wid, int nf, int lane)
{
    return (const h8*)(w + (size_t)((ks * 16 + (wid * 4 + nf)) * 64 + lane) * 8);
}

// Barrier that does NOT drain vmcnt: keeps cross-layer B-prefetch loads in
// flight. lgkmcnt(0) orders all LDS reads/writes (WAR and RAW both safe);
// sched_barrier(0) stops the compiler from moving LDS ops across it.
__device__ __forceinline__ void barrier_nodrain()
{
    asm volatile("s_waitcnt lgkmcnt(0)" ::: "memory");
    __builtin_amdgcn_s_barrier();
    __builtin_amdgcn_sched_barrier(0);
}

// MODE: 0 = A from hbuf, 1 = A from xbuf (layer 0), 2 = hbuf then xbuf (layer 5)
// pf: depth-3 rolling prefetch. Global kstep g = gbase + ks; slot = g % 3;
// GB3 = gbase % 3 (compile-time). On entry slots hold globals g..g+2; each
// ks consumes slot (GB3+ks)%3 and refills it with global g+ks+3 (this layer's
// ks+3, or the next layer's ks+3-KSTEPS).
template <int KSTEPS, int MODE, int GB3, bool LAST>
__device__ __forceinline__ void mlp_layer(_Float16 (&hbuf)[64][264], _Float16 (&xbuf)[64][72],
                                          const _Float16* __restrict__ wfrag,
                                          const _Float16* __restrict__ wnext,
                                          const float* __restrict__ bias,
                                          int wid, int lane, h8 (&pf)[3][4])
{
    const int lg = lane >> 4, ln = lane & 15;

    // bias early (no fresh global load in the epilogue)
    float bv[4];
#pragma unroll
    for (int nf = 0; nf < 4; ++nf) bv[nf] = bias[wid * 64 + nf * 16 + ln];

    f4 acc[4][4];
#pragma unroll
    for (int mf = 0; mf < 4; ++mf)
#pragma unroll
        for (int nf = 0; nf < 4; ++nf)
#pragma unroll
            for (int i = 0; i < 4; ++i) acc[mf][nf][i] = 0.f;

#pragma unroll
    for (int ks = 0; ks < KSTEPS; ++ks) {
        const int slot = (GB3 + ks) % 3;      // folds to constant after unroll
        __builtin_amdgcn_s_setprio(1);
#pragma unroll
        for (int mf = 0; mf < 4; ++mf) {
            const _Float16* ap;
            if constexpr (MODE == 1) {
                ap = &xbuf[mf * 16 + ln][ks * 32 + lg * 8];
            } else if constexpr (MODE == 2) {
                ap = (ks < 8) ? &hbuf[mf * 16 + ln][ks * 32 + lg * 8]
                              : &xbuf[mf * 16 + ln][(ks - 8) * 32 + lg * 8];
            } else {
                ap = &hbuf[mf * 16 + ln][ks * 32 + lg * 8];
            }
            h8 afr = *(const h8*)ap;
#pragma unroll
            for (int nf = 0; nf < 4; ++nf)
                acc[mf][nf] = __builtin_amdgcn_mfma_f32_16x16x32_f16(afr, pf[slot][nf], acc[mf][nf], 0, 0, 0);
        }
        __builtin_amdgcn_s_setprio(0);
        // refill the slot just consumed with global kstep g+3
        if (ks + 3 < KSTEPS) {
#pragma unroll
            for (int nf = 0; nf < 4; ++nf)
                pf[slot][nf] = *bfrag_ptr(wfrag, ks + 3, wid, nf, lane);
        } else if (!LAST) {
#pragma unroll
            for (int nf = 0; nf < 4; ++nf)
                pf[slot][nf] = *bfrag_ptr(wnext, ks + 3 - KSTEPS, wid, nf, lane);
        }
    }

    barrier_nodrain();   // WAR: everyone done reading hbuf (lgkmcnt covers reads)

#pragma unroll
    for (int nf = 0; nf < 4; ++nf) {
#pragma unroll
        for (int mf = 0; mf < 4; ++mf) {
#pragma unroll
            for (int i = 0; i < 4; ++i) {
                float v = acc[mf][nf][i] + bv[nf];  // bias in fp32
                v = fmaxf(v, 0.f);                  // relu in fp32
                // C layout (m89-verified): row = (lane>>4)*4 + reg, col = lane&15
                hbuf[mf * 16 + lg * 4 + i][wid * 64 + nf * 16 + ln] = (_Float16)v;
            }
        }
    }
    barrier_nodrain();   // RAW: writes visible before next layer's reads
}

__global__ __launch_bounds__(256, 3) void nerf_fused(
    const float* __restrict__ x,
    const float* __restrict__ b0, const float* __restrict__ b1, const float* __restrict__ b2,
    const float* __restrict__ b3, const float* __restrict__ b4, const float* __restrict__ b5,
    const float* __restrict__ b6, const float* __restrict__ b7, const float* __restrict__ bout,
    const _Float16* __restrict__ wf,
    float* __restrict__ out)
{
    __shared__ _Float16 hbuf[64][264];   // 256 + 8 pad halves per row (proven layout)
    __shared__ _Float16 xbuf[64][72];    // 64 (63 real + 1 zero) + pad

    const int tid  = threadIdx.x;
    const int wid  = tid >> 6;
    const int lane = tid & 63;
    const int lg   = lane >> 4, ln = lane & 15;
    const int row0 = blockIdx.x * 64;

    // prologue: globals 0,1,2 = L0 ks0, L0 ks1, L1 ks0 into slots 0,1,2
    h8 pf[3][4];
#pragma unroll
    for (int nf = 0; nf < 4; ++nf) {
        pf[0][nf] = *bfrag_ptr(wf + OFF_L0, 0, wid, nf, lane);
        pf[1][nf] = *bfrag_ptr(wf + OFF_L0, 1, wid, nf, lane);
        pf[2][nf] = *bfrag_ptr(wf + OFF_L1, 0, wid, nf, lane);
    }

    // stage x[:, 0:63] -> fp16, zero-pad col 63
    for (int idx = tid; idx < 64 * 64; idx += 256) {
        int r = idx >> 6, c = idx & 63;
        float v = (c < 63) ? x[(size_t)(row0 + r) * 90 + c] : 0.f;
        xbuf[r][c] = (_Float16)v;
    }
    barrier_nodrain();

    // gbase per layer: L0=0,L1=2,L2=10,L3=18,L4=26,L5=34,L6=44,L7=52 -> %3:
    mlp_layer<2,  1, 0, false>(hbuf, xbuf, wf + OFF_L0, wf + OFF_L1, b0, wid, lane, pf);
    mlp_layer<8,  0, 2, false>(hbuf, xbuf, wf + OFF_L1, wf + OFF_L2, b1, wid, lane, pf);
    mlp_layer<8,  0, 1, false>(hbuf, xbuf, wf + OFF_L2, wf + OFF_L3, b2, wid, lane, pf);
    mlp_layer<8,  0, 0, false>(hbuf, xbuf, wf + OFF_L3, wf + OFF_L4, b3, wid, lane, pf);
    mlp_layer<8,  0, 2, false>(hbuf, xbuf, wf + OFF_L4, wf + OFF_L5, b4, wid, lane, pf);
    mlp_layer<10, 2, 1, false>(hbuf, xbuf, wf + OFF_L5, wf + OFF_L6, b5, wid, lane, pf);
    mlp_layer<8,  0, 2, false>(hbuf, xbuf, wf + OFF_L6, wf + OFF_L7, b6, wid, lane, pf);
    mlp_layer<8,  0, 1, true >(hbuf, xbuf, wf + OFF_L7, wf + OFF_L7, b7, wid, lane, pf);

    // output layer 256 -> 4 (padded to 16 cols), row-split: wave wid owns rows [16*wid, 16*wid+16)
    f4 oacc;
#pragma unroll
    for (int i = 0; i < 4; ++i) oacc[i] = 0.f;
#pragma unroll
    for (int ks = 0; ks < 8; ++ks) {
        h8 bfr = *(const h8*)(wf + OFF_OUT + (size_t)(ks * 64 + lane) * 8);
        h8 afr = *(const h8*)&hbuf[wid * 16 + ln][ks * 32 + lg * 8];
        oacc = __builtin_amdgcn_mfma_f32_16x16x32_f16(afr, bfr, oacc, 0, 0, 0);
    }
    if (ln < 4) {
        float bo = bout[ln];
#pragma unroll
        for (int i = 0; i < 4; ++i) {
            int r = row0 + wid * 16 + lg * 4 + i;
            out[(size_t)r * 4 + ln] = oacc[i] + bo;
        }
    }
}

extern "C" void kernel_launch(void* const* d_in, const int* in_sizes, int n_in,
                              void* d_out, int out_size, void* d_ws, size_t ws_size,
                              hipStream_t stream)
{
    const float* x = (const float*)d_in[0];
    const float* W[9];
    const float* b[9];
    for (int i = 0; i < 8; ++i) {
        W[i] = (const float*)d_in[1 + 2 * i];
        b[i] = (const float*)d_in[2 + 2 * i];
    }
    W[8] = (const float*)d_in[17];   // Wout
    b[8] = (const float*)d_in[18];   // bout

    _Float16* wf = (_Float16*)d_ws;

    nerf_prep<<<(TOT_GROUPS + 255) / 256, 256, 0, stream>>>(
        W[0], W[1], W[2], W[3], W[4], W[5], W[6], W[7], W[8], wf);

    nerf_fused<<<262144 / 64, 256, 0, stream>>>(
        x, b[0], b[1], b[2], b[3], b[4], b[5], b[6], b[7], b[8], wf,
        (float*)d_out);
}

// Round 8
// 234.899 us; speedup vs baseline: 1.2870x; 1.0109x over previous
//
#include <hip/hip_runtime.h>

// ---------------------------------------------------------------------------
// Fused NeRF MLP forward: 262144 rows, 63-in, 8x256 hidden + skip at L4->L5,
// 4-dim output. fp16 MFMA (16x16x32) with fp32 accumulation.
//
// R8 = R7 base with SWAPPED MFMA operands in the hidden layers:
//   mfma(W_frag, h_frag) -> D[ncol][sample]; C-layout (m89: row=(lg*4)+reg,
//   col=ln) puts 4 consecutive ncols in each lane's 4 acc regs, so the
//   epilogue packs relu(acc)+cvt into ONE ds_write_b64 (16 writes/wave-layer
//   vs 64 scalar b16). Bias becomes a float4 load per cf that INITIALIZES the
//   accumulator (removes 64 zero-inits and 64 epilogue adds per wave-layer).
//   The k-bijection is A/B-symmetric, so the weight file and the h-frag read
//   addresses are byte-identical to R7 - only arg order/epilogue change.
// R5/R6/R7 lessons: occupancy, tile rotation, prefetch depth, barrier drain,
// setprio all non-binding; the per-wave non-MFMA overhead is the target.
// ---------------------------------------------------------------------------

typedef _Float16 h8 __attribute__((ext_vector_type(8)));
typedef float f4 __attribute__((ext_vector_type(4)));

// fragment-linear weight offsets, in halves:
// L0 K=64, L1..L4 K=256, L5 K=320, L6,L7 K=256, OUT K=256 (NF=1, n padded to 16)
#define OFF_L0   0
#define OFF_L1   16384
#define OFF_L2   81920
#define OFF_L3   147456
#define OFF_L4   212992
#define OFF_L5   278528
#define OFF_L6   360448
#define OFF_L7   425984
#define OFF_OUT  491520
#define TOT_HALVES 495616
#define TOT_GROUPS (TOT_HALVES / 8)   // 61952

__global__ void nerf_prep(const float* __restrict__ W0, const float* __restrict__ W1,
                          const float* __restrict__ W2, const float* __restrict__ W3,
                          const float* __restrict__ W4, const float* __restrict__ W5,
                          const float* __restrict__ W6, const float* __restrict__ W7,
                          const float* __restrict__ Wout, _Float16* __restrict__ wf)
{
    int g = blockIdx.x * 256 + threadIdx.x;     // one 8-half fragment group
    if (g >= TOT_GROUPS) return;

    const int bounds[10] = {0, 2048, 10240, 18432, 26624, 34816, 45056, 53248, 61440, 61952};
    const float* Ws[9] = {W0, W1, W2, W3, W4, W5, W6, W7, Wout};

    int L = 0;
    while (L < 8 && g >= bounds[L + 1]) ++L;

    int t    = g - bounds[L];
    int lane = t & 63;
    int q    = t >> 6;
    int NF   = (L == 8) ? 1 : 16;
    int nf   = q % NF;
    int ks   = q / NF;
    int n    = nf * 16 + (lane & 15);
    int k0   = ks * 32 + (lane >> 4) * 8;

    const float* W = Ws[L];
    h8 v;
#pragma unroll
    for (int i = 0; i < 8; ++i) {
        int k = k0 + i;
        float val = 0.f;
        if (L == 0) {
            if (k < 63) val = W[k * 256 + n];                 // 63x256, pad k=63
        } else if (L == 5) {
            // k' < 256 -> h part (orig row 63+k'); k' >= 256 -> x part (orig row k'-256)
            if (k < 256)            val = W[(63 + k) * 256 + n];
            else if ((k - 256) < 63) val = W[(k - 256) * 256 + n];
        } else if (L == 8) {
            if (n < 4) val = W[k * 4 + n];                    // 256x4, pad n to 16
        } else {
            val = W[k * 256 + n];                             // 256x256
        }
        v[i] = (_Float16)val;
    }
    *(h8*)(wf + (size_t)g * 8) = v;
}

__device__ __forceinline__ const h8* bfrag_ptr(const _Float16* __restrict__ w,
                                               int ks, int wid, int nf, int lane)
{
    return (const h8*)(w + (size_t)((ks * 16 + (wid * 4 + nf)) * 64 + lane) * 8);
}

// Barrier that does NOT drain vmcnt: keeps cross-layer B-prefetch loads in
// flight. lgkmcnt(0) orders all LDS reads/writes (WAR and RAW both safe);
// sched_barrier(0) stops the compiler from moving LDS ops across it.
__device__ __forceinline__ void barrier_nodrain()
{
    asm volatile("s_waitcnt lgkmcnt(0)" ::: "memory");
    __builtin_amdgcn_s_barrier();
    __builtin_amdgcn_sched_barrier(0);
}

// MODE: 0 = h from hbuf, 1 = h from xbuf (layer 0), 2 = hbuf then xbuf (layer 5)
// pf: depth-3 rolling prefetch of W-fragments (consumed as MFMA **A** operand).
// acc[cf][sf]: D[ncol][sample] per fragment pair; initialized with bias.
template <int KSTEPS, int MODE, int GB3, bool LAST>
__device__ __forceinline__ void mlp_layer(_Float16 (&hbuf)[64][264], _Float16 (&xbuf)[64][72],
                                          const _Float16* __restrict__ wfrag,
                                          const _Float16* __restrict__ wnext,
                                          const float* __restrict__ bias,
                                          int wid, int lane, h8 (&pf)[3][4])
{
    const int lg = lane >> 4, ln = lane & 15;

    // bias as float4 per cf: ncols wid*64 + cf*16 + lg*4 + (0..3)  (16B aligned)
    f4 bv[4];
#pragma unroll
    for (int cf = 0; cf < 4; ++cf)
        bv[cf] = *(const f4*)&bias[wid * 64 + cf * 16 + lg * 4];

    // accumulator INITIALIZED with bias (saves zero-init + epilogue add)
    f4 acc[4][4];   // [cf][sf]
#pragma unroll
    for (int cf = 0; cf < 4; ++cf)
#pragma unroll
        for (int sf = 0; sf < 4; ++sf)
            acc[cf][sf] = bv[cf];

#pragma unroll
    for (int ks = 0; ks < KSTEPS; ++ks) {
        const int slot = (GB3 + ks) % 3;      // folds to constant after unroll
        __builtin_amdgcn_s_setprio(1);
        h8 hfr[4];
#pragma unroll
        for (int sf = 0; sf < 4; ++sf) {
            const _Float16* ap;
            if constexpr (MODE == 1) {
                ap = &xbuf[sf * 16 + ln][ks * 32 + lg * 8];
            } else if constexpr (MODE == 2) {
                ap = (ks < 8) ? &hbuf[sf * 16 + ln][ks * 32 + lg * 8]
                              : &xbuf[sf * 16 + ln][(ks - 8) * 32 + lg * 8];
            } else {
                ap = &hbuf[sf * 16 + ln][ks * 32 + lg * 8];
            }
            hfr[sf] = *(const h8*)ap;
        }
#pragma unroll
        for (int cf = 0; cf < 4; ++cf)
#pragma unroll
            for (int sf = 0; sf < 4; ++sf)
                acc[cf][sf] = __builtin_amdgcn_mfma_f32_16x16x32_f16(pf[slot][cf], hfr[sf], acc[cf][sf], 0, 0, 0);
        __builtin_amdgcn_s_setprio(0);
        // refill the slot just consumed with global kstep g+3
        if (ks + 3 < KSTEPS) {
#pragma unroll
            for (int cf = 0; cf < 4; ++cf)
                pf[slot][cf] = *bfrag_ptr(wfrag, ks + 3, wid, cf, lane);
        } else if (!LAST) {
#pragma unroll
            for (int cf = 0; cf < 4; ++cf)
                pf[slot][cf] = *bfrag_ptr(wnext, ks + 3 - KSTEPS, wid, cf, lane);
        }
    }

    barrier_nodrain();   // WAR: everyone done reading hbuf

    // packed epilogue: relu + cvt, 4 ncols -> one ds_write_b64 per (cf,sf)
    // D layout (m89): col=ln=sample-within-16, row=lg*4+reg=ncol-within-16
#pragma unroll
    for (int cf = 0; cf < 4; ++cf) {
#pragma unroll
        for (int sf = 0; sf < 4; ++sf) {
            union { _Float16 h[4]; unsigned long long u; } p;
#pragma unroll
            for (int i = 0; i < 4; ++i)
                p.h[i] = (_Float16)fmaxf(acc[cf][sf][i], 0.f);
            *(unsigned long long*)&hbuf[sf * 16 + ln][wid * 64 + cf * 16 + lg * 4] = p.u;
        }
    }
    barrier_nodrain();   // RAW: writes visible before next layer's reads
}

__global__ __launch_bounds__(256, 3) void nerf_fused(
    const float* __restrict__ x,
    const float* __restrict__ b0, const float* __restrict__ b1, const float* __restrict__ b2,
    const float* __restrict__ b3, const float* __restrict__ b4, const float* __restrict__ b5,
    const float* __restrict__ b6, const float* __restrict__ b7, const float* __restrict__ bout,
    const _Float16* __restrict__ wf,
    float* __restrict__ out)
{
    __shared__ _Float16 hbuf[64][264];   // 256 + 8 pad halves per row (proven layout)
    __shared__ _Float16 xbuf[64][72];    // 64 (63 real + 1 zero) + pad

    const int tid  = threadIdx.x;
    const int wid  = tid >> 6;
    const int lane = tid & 63;
    const int lg   = lane >> 4, ln = lane & 15;
    const int row0 = blockIdx.x * 64;

    // prologue: globals 0,1,2 = L0 ks0, L0 ks1, L1 ks0 into slots 0,1,2
    h8 pf[3][4];
#pragma unroll
    for (int cf = 0; cf < 4; ++cf) {
        pf[0][cf] = *bfrag_ptr(wf + OFF_L0, 0, wid, cf, lane);
        pf[1][cf] = *bfrag_ptr(wf + OFF_L0, 1, wid, cf, lane);
        pf[2][cf] = *bfrag_ptr(wf + OFF_L1, 0, wid, cf, lane);
    }

    // stage x[:, 0:63] -> fp16, zero-pad col 63
    for (int idx = tid; idx < 64 * 64; idx += 256) {
        int r = idx >> 6, c = idx & 63;
        float v = (c < 63) ? x[(size_t)(row0 + r) * 90 + c] : 0.f;
        xbuf[r][c] = (_Float16)v;
    }
    barrier_nodrain();

    // gbase per layer: L0=0,L1=2,L2=10,L3=18,L4=26,L5=34,L6=44,L7=52 -> %3:
    mlp_layer<2,  1, 0, false>(hbuf, xbuf, wf + OFF_L0, wf + OFF_L1, b0, wid, lane, pf);
    mlp_layer<8,  0, 2, false>(hbuf, xbuf, wf + OFF_L1, wf + OFF_L2, b1, wid, lane, pf);
    mlp_layer<8,  0, 1, false>(hbuf, xbuf, wf + OFF_L2, wf + OFF_L3, b2, wid, lane, pf);
    mlp_layer<8,  0, 0, false>(hbuf, xbuf, wf + OFF_L3, wf + OFF_L4, b3, wid, lane, pf);
    mlp_layer<8,  0, 2, false>(hbuf, xbuf, wf + OFF_L4, wf + OFF_L5, b4, wid, lane, pf);
    mlp_layer<10, 2, 1, false>(hbuf, xbuf, wf + OFF_L5, wf + OFF_L6, b5, wid, lane, pf);
    mlp_layer<8,  0, 2, false>(hbuf, xbuf, wf + OFF_L6, wf + OFF_L7, b6, wid, lane, pf);
    mlp_layer<8,  0, 1, true >(hbuf, xbuf, wf + OFF_L7, wf + OFF_L7, b7, wid, lane, pf);

    // output layer 256 -> 4 (padded to 16 cols), UNswapped (original path):
    // wave wid owns rows [16*wid, 16*wid+16)
    f4 oacc;
#pragma unroll
    for (int i = 0; i < 4; ++i) oacc[i] = 0.f;
#pragma unroll
    for (int ks = 0; ks < 8; ++ks) {
        h8 bfr = *(const h8*)(wf + OFF_OUT + (size_t)(ks * 64 + lane) * 8);
        h8 afr = *(const h8*)&hbuf[wid * 16 + ln][ks * 32 + lg * 8];
        oacc = __builtin_amdgcn_mfma_f32_16x16x32_f16(afr, bfr, oacc, 0, 0, 0);
    }
    if (ln < 4) {
        float bo = bout[ln];
#pragma unroll
        for (int i = 0; i < 4; ++i) {
            int r = row0 + wid * 16 + lg * 4 + i;
            out[(size_t)r * 4 + ln] = oacc[i] + bo;
        }
    }
}

extern "C" void kernel_launch(void* const* d_in, const int* in_sizes, int n_in,
                              void* d_out, int out_size, void* d_ws, size_t ws_size,
                              hipStream_t stream)
{
    const float* x = (const float*)d_in[0];
    const float* W[9];
    const float* b[9];
    for (int i = 0; i < 8; ++i) {
        W[i] = (const float*)d_in[1 + 2 * i];
        b[i] = (const float*)d_in[2 + 2 * i];
    }
    W[8] = (const float*)d_in[17];   // Wout
    b[8] = (const float*)d_in[18];   // bout

    _Float16* wf = (_Float16*)d_ws;

    nerf_prep<<<(TOT_GROUPS + 255) / 256, 256, 0, stream>>>(
        W[0], W[1], W[2], W[3], W[4], W[5], W[6], W[7], W[8], wf);

    nerf_fused<<<262144 / 64, 256, 0, stream>>>(
        x, b[0], b[1], b[2], b[3], b[4], b[5], b[6], b[7], b[8], wf,
        (float*)d_out);
}